// Round 1
// baseline (127.282 us; speedup 1.0000x reference)
//
#include <hip/hip_runtime.h>
#include <math.h>

#define B 4
#define C 384
#define HIN 224
#define WIN 224
#define KS 14
#define HB 16
#define WBL 16
#define P 196  // KS*KS

// ---------------------------------------------------------------------------
// Kernel 1: rowsum[b,h,w] = sum_c hr[b,c,h,w] * attn_w[c]
// One block per (b,h) row. 4 waves split c; lanes 0..55 hold float4 columns.
// ---------------------------------------------------------------------------
__global__ __launch_bounds__(256) void k_rowsum(const float* __restrict__ hr,
                                                const float* __restrict__ attn_w,
                                                float* __restrict__ rowsum) {
    __shared__ float wlds[C];
    __shared__ float4 red[224];
    const int blk = blockIdx.x;        // 0 .. B*HIN-1
    const int b = blk / HIN, h = blk % HIN;
    const int tid = threadIdx.x;
    for (int i = tid; i < C; i += 256) wlds[i] = attn_w[i];
    __syncthreads();

    const int wave = tid >> 6, lane = tid & 63;
    float4 acc = make_float4(0.f, 0.f, 0.f, 0.f);
    if (lane < 56) {
        const float* base = hr + (size_t)b * C * (HIN * WIN) + (size_t)h * WIN + lane * 4;
        for (int c = wave; c < C; c += 4) {
            const float4 v = *reinterpret_cast<const float4*>(base + (size_t)c * (HIN * WIN));
            const float wc = wlds[c];
            acc.x += v.x * wc; acc.y += v.y * wc; acc.z += v.z * wc; acc.w += v.w * wc;
        }
        red[wave * 56 + lane] = acc;
    }
    __syncthreads();
    if (tid < 56) {
        const float4 a0 = red[tid], a1 = red[56 + tid], a2 = red[112 + tid], a3 = red[168 + tid];
        float4 s;
        s.x = a0.x + a1.x + a2.x + a3.x;
        s.y = a0.y + a1.y + a2.y + a3.y;
        s.z = a0.z + a1.z + a2.z + a3.z;
        s.w = a0.w + a1.w + a2.w + a3.w;
        reinterpret_cast<float4*>(rowsum + (size_t)blk * WIN)[tid] = s;
    }
}

// ---------------------------------------------------------------------------
// Kernel 2: logits -> softmax -> attn[b,hb,wb,p]
// One block per (b,hb,wb). tid<196 handles one p.
// ---------------------------------------------------------------------------
__global__ __launch_bounds__(256) void k_softmax(const float* __restrict__ rowsum,
                                                 const float* __restrict__ attn_b,
                                                 const float* __restrict__ w_kk,
                                                 const float* __restrict__ b_kk,
                                                 const int* __restrict__ mask,
                                                 float* __restrict__ attn) {
    const int blk = blockIdx.x;        // 0 .. B*HB*WBL-1
    const int wb = blk % WBL;
    const int hb = (blk / WBL) % HB;
    const int b = blk / (WBL * HB);
    const int tid = threadIdx.x;

    float logit = 0.f;
    float l = -INFINITY;
    if (tid < P) {
        const int ki = tid / KS, kj = tid % KS;
        const float rv = rowsum[((size_t)b * HIN + hb * KS + ki) * WIN + wb * KS + kj];
        const float m = mask[(b * HB + hb) * WBL + wb] ? 1.f : 0.f;
        logit = (rv + attn_b[0]) * m * w_kk[tid] + b_kk[tid];
        l = logit;
    }

    __shared__ float smax[4], ssum[4];
    float v = l;
    #pragma unroll
    for (int off = 32; off; off >>= 1) v = fmaxf(v, __shfl_xor(v, off));
    if ((tid & 63) == 0) smax[tid >> 6] = v;
    __syncthreads();
    const float bm = fmaxf(fmaxf(smax[0], smax[1]), fmaxf(smax[2], smax[3]));

    float e = (tid < P) ? expf(logit - bm) : 0.f;
    float s = e;
    #pragma unroll
    for (int off = 32; off; off >>= 1) s += __shfl_xor(s, off);
    if ((tid & 63) == 0) ssum[tid >> 6] = s;
    __syncthreads();
    const float bs = ssum[0] + ssum[1] + ssum[2] + ssum[3];

    if (tid < P) attn[(size_t)blk * P + tid] = e / bs;
}

// ---------------------------------------------------------------------------
// Kernel 3: out[b,c,hb,wb] = sum_p hr_patch[p] * attn[b,hb,wb,p]
// One block per (b,c,hb). attn strip (16*196 floats) staged in LDS.
// Lanes 0..223 each own one input column, accumulate over 14 rows, then a
// segmented LDS reduce (14 -> 1) produces the 16 wb outputs.
// ---------------------------------------------------------------------------
__global__ __launch_bounds__(256) void k_weighted(const float* __restrict__ hr,
                                                  const float* __restrict__ attn,
                                                  float* __restrict__ out) {
    __shared__ float alds[WBL * P];    // 3136 floats
    __shared__ float colsum[WIN];      // 224 floats
    const int blk = blockIdx.x;        // 0 .. B*C*HB-1
    const int hb = blk % HB;
    const int c = (blk / HB) % C;
    const int b = blk / (HB * C);
    const int tid = threadIdx.x;

    const float* abase = attn + ((size_t)b * HB + hb) * WBL * P;
    for (int i = tid; i < WBL * P; i += 256) alds[i] = abase[i];
    __syncthreads();

    if (tid < WIN) {
        const int wb = tid / KS, kj = tid % KS;
        const float* hbase = hr + ((size_t)(b * C + c) * HIN + hb * KS) * WIN + tid;
        const float* arow = alds + wb * P + kj;
        float acc = 0.f;
        #pragma unroll
        for (int ki = 0; ki < KS; ++ki)
            acc += hbase[(size_t)ki * WIN] * arow[ki * KS];
        colsum[tid] = acc;
    }
    __syncthreads();
    if (tid < WBL) {
        float s = 0.f;
        #pragma unroll
        for (int kj = 0; kj < KS; ++kj) s += colsum[tid * KS + kj];
        out[((size_t)(b * C + c) * HB + hb) * WBL + tid] = s;
    }
}

extern "C" void kernel_launch(void* const* d_in, const int* in_sizes, int n_in,
                              void* d_out, int out_size, void* d_ws, size_t ws_size,
                              hipStream_t stream) {
    const float* hr      = (const float*)d_in[0];  // (4,384,224,224)
    // d_in[1] = guidance (unused)
    const float* attn_w  = (const float*)d_in[2];  // (1,384)
    const float* attn_b  = (const float*)d_in[3];  // (1,)
    const float* w_kk    = (const float*)d_in[4];  // (14,14)
    const float* b_kk    = (const float*)d_in[5];  // (14,14)
    const int*   mask    = (const int*)d_in[6];    // (4,16,16,1) bool->int
    float* out = (float*)d_out;                    // (4,384,16,16)

    float* rowsum = (float*)d_ws;                          // B*HIN*WIN floats
    float* attn   = rowsum + (size_t)B * HIN * WIN;        // B*HB*WBL*P floats

    k_rowsum<<<B * HIN, 256, 0, stream>>>(hr, attn_w, rowsum);
    k_softmax<<<B * HB * WBL, 256, 0, stream>>>(rowsum, attn_b, w_kk, b_kk, mask, attn);
    k_weighted<<<B * C * HB, 256, 0, stream>>>(hr, attn, out);
}